// Round 4
// baseline (12204.833 us; speedup 1.0000x reference)
//
#include <hip/hip_runtime.h>
#include <hip/hip_bf16.h>
#include <math.h>

// Problem dims: B=256, K(beams)=128, H=512, D=64, DEPTH=16
#define NB    256
#define NK    128
#define NH    512
#define ND    64
#define NDEPTH 16
#define BKROWS (NB*NK)          // 32768
#define TEMPD 20.0

// ---------------- prep: pre-convert weights to f64.
// Wsw[cb][k][cl] = (double)Whh[k][cb*128+cl]   (4 x 512 x 128)
// Wld[k][d]      = (double)Wl[k][d]            (512 x 64)
__global__ void k_prep(const float* __restrict__ Whh, const float* __restrict__ Wl,
                       double* __restrict__ Wsw, double* __restrict__ Wld) {
    int idx = blockIdx.x * 256 + threadIdx.x;      // 0..262143
    int k = idx >> 9;                              // 0..511
    int c = idx & 511;
    int cb = c >> 7, cl = c & 127;
    Wsw[((size_t)cb * NH + k) * 128 + cl] = (double)Whh[idx];
    if (idx < NH * ND) Wld[idx] = (double)Wl[idx];
}

// ---------------- init
__global__ void k_init(const float* __restrict__ root, float* __restrict__ states,
                       double* __restrict__ scores, unsigned char* __restrict__ hist) {
    int idx = blockIdx.x * 256 + threadIdx.x;          // 0 .. 16,777,215
    states[idx] = root[idx & (NH - 1)];
    if (idx < BKROWS) scores[idx] = ((idx & (NK - 1)) == 0) ? 0.0 : -1e9;
    if (idx < BKROWS * NDEPTH) hist[idx] = 0;
}

// ---------------- K1: logits GEMM (f64) + log-softmax + cand = score + logp
// grid: 512 blocks (64 rows each), 256 threads. Thread: 8 rows x 2 cols (tc, tc+32).
__global__ void __launch_bounds__(256, 3)
k_logits(const float* __restrict__ states,
         const double* __restrict__ Wld,    // [H][D] f64
         const float* __restrict__ bl,      // [D]
         const double* __restrict__ scores, // [B*K]
         double* __restrict__ cand)         // [B*K][D]
{
    __shared__ double wl[32][64];   // 16 KB
    __shared__ double st[64][32];   // 16 KB
    const int rowb = blockIdx.x * 64;
    const int t    = threadIdx.x;
    const int tc   = t & 31;
    const int rg   = t >> 5;

    double acc[8][2];
    #pragma unroll
    for (int i = 0; i < 8; ++i) { acc[i][0] = 0.0; acc[i][1] = 0.0; }

    for (int kc = 0; kc < NH; kc += 32) {
        #pragma unroll
        for (int j = 0; j < 4; ++j) {          // W tile: 1024 double2 copies, linear b128
            int idx = j * 256 + t;
            int row = idx >> 5, cp = idx & 31;
            double2 d = *(const double2*)&Wld[(size_t)(kc + row) * ND + 2 * cp];
            *(double2*)&wl[row][2 * cp] = d;
        }
        #pragma unroll
        for (int j = 0; j < 4; ++j) {          // S tile: float2 -> double2, linear b128
            int idx = j * 256 + t;
            int r = idx >> 4, cp = idx & 15;
            float2 v = *(const float2*)&states[(size_t)(rowb + r) * NH + kc + 2 * cp];
            double2 d; d.x = (double)v.x; d.y = (double)v.y;
            *(double2*)&st[r][2 * cp] = d;
        }
        __syncthreads();
        #pragma unroll 4
        for (int hh = 0; hh < 32; hh += 2) {
            double w00 = wl[hh][tc],   w01 = wl[hh][tc+32];
            double w10 = wl[hh+1][tc], w11 = wl[hh+1][tc+32];
            #pragma unroll
            for (int i = 0; i < 8; ++i) {
                double2 s = *(const double2*)&st[rg*8+i][hh];
                acc[i][0] = fma(s.x, w00, acc[i][0]);
                acc[i][1] = fma(s.x, w01, acc[i][1]);
                acc[i][0] = fma(s.y, w10, acc[i][0]);
                acc[i][1] = fma(s.y, w11, acc[i][1]);
            }
        }
        __syncthreads();
    }

    const double bd0 = (double)bl[tc];
    const double bd1 = (double)bl[tc + 32];
    #pragma unroll
    for (int i = 0; i < 8; ++i) {
        int row = rowb + rg * 8 + i;
        double x0 = (acc[i][0] + bd0) / TEMPD;
        double x1 = (acc[i][1] + bd1) / TEMPD;
        double m = fmax(x0, x1);
        for (int off = 1; off <= 16; off <<= 1) m = fmax(m, __shfl_xor(m, off, 64));
        double e = exp(x0 - m) + exp(x1 - m);
        for (int off = 1; off <= 16; off <<= 1) e += __shfl_xor(e, off, 64);
        double ls = log(e);
        double sc = scores[row];
        cand[(size_t)row * ND + tc]      = sc + x0 - m - ls;
        cand[(size_t)row * ND + tc + 32] = sc + x1 - m - ls;
    }
}

// ---------------- K2: per-batch top-128 of 8192 (value desc, index asc) + hist gather
__global__ void k_topk(const double* __restrict__ cand,    // [B][8192]
                       double* __restrict__ scores,
                       int* __restrict__ parent, int* __restrict__ decs,
                       const unsigned char* __restrict__ hist_in,
                       unsigned char* __restrict__ hist_out,
                       int tstep)
{
    __shared__ double lv[2][4];
    __shared__ int    li_[2][4];
    __shared__ int sp[NK], sd[NK];

    const int b    = blockIdx.x;
    const int t    = threadIdx.x;
    const int lane = t & 63;
    const int wv   = t >> 6;
    const double* cb = cand + (size_t)b * (NK * ND);

    double v[32];
    #pragma unroll
    for (int j = 0; j < 32; ++j) v[j] = cb[j * 256 + t];

    double mv = v[0]; int mi = t;
    #pragma unroll
    for (int j = 1; j < 32; ++j)
        if (v[j] > mv) { mv = v[j]; mi = j * 256 + t; }

    for (int it = 0; it < NK; ++it) {
        const int p = it & 1;
        double m = mv; int idx = mi;
        #pragma unroll
        for (int off = 1; off <= 32; off <<= 1) {
            double m2 = __shfl_xor(m, off, 64);
            int    i2 = __shfl_xor(idx, off, 64);
            if (m2 > m || (m2 == m && i2 < idx)) { m = m2; idx = i2; }
        }
        if (lane == 0) { lv[p][wv] = m; li_[p][wv] = idx; }
        __syncthreads();
        double bm = lv[p][0]; int bi = li_[p][0];
        #pragma unroll
        for (int w = 1; w < 4; ++w) {
            double m2 = lv[p][w]; int i2 = li_[p][w];
            if (m2 > bm || (m2 == bm && i2 < bi)) { bm = m2; bi = i2; }
        }
        if (t == 0) {
            scores[b * NK + it] = bm;
            parent[b * NK + it] = bi >> 6;
            decs  [b * NK + it] = bi & 63;
            sp[it] = bi >> 6; sd[it] = bi & 63;
        }
        if ((bi & 255) == t) {
            #pragma unroll
            for (int j = 0; j < 32; ++j) if (j * 256 + t == bi) v[j] = -INFINITY;
            mv = v[0]; mi = t;
            #pragma unroll
            for (int j = 1; j < 32; ++j)
                if (v[j] > mv) { mv = v[j]; mi = j * 256 + t; }
        }
    }
    __syncthreads();

    for (int i = t; i < NK * NDEPTH; i += 256) {
        int k = i >> 4, j = i & 15;
        hist_out[(b * NK + k) * NDEPTH + j] = (j == tstep) ? (unsigned char)sd[k]
                                            : hist_in[(b * NK + sp[k]) * NDEPTH + j];
    }
}

// ---------------- K3: vector f64. new_states = tanh(states[parent] @ W_hh + b_hh + emb[dec])
// grid (512, 4), 256 threads. Block 64 rows x 128 cols; thread 8 rows x 4 cols.
// Inner loop and accumulation order identical to the round-2 validated kernel.
__global__ void __launch_bounds__(256, 3)
k_rnn(const float* __restrict__ states_in,
      const double* __restrict__ Wsw,  // [4][512][128] f64 (pre-converted)
      const float* __restrict__ bhh,
      const float* __restrict__ emb,   // [D][H]
      const int* __restrict__ parent, const int* __restrict__ decs,
      float* __restrict__ states_out)
{
    __shared__ double wt[32][128];   // 32 KB
    __shared__ double st[64][32];    // 16 KB
    __shared__ int sp[64], sd[64];

    const int rowb = blockIdx.x * 64;
    const int cbk  = blockIdx.y;
    const int colb = cbk * 128;
    const int t    = threadIdx.x;
    const int tc   = t & 31;
    const int rg   = t >> 5;
    if (t < 64) { sp[t] = parent[rowb + t]; sd[t] = decs[rowb + t]; }
    __syncthreads();

    // per-thread gathered state rows for S staging
    int srow[4];
    #pragma unroll
    for (int j = 0; j < 4; ++j) {
        int idx = j * 256 + t;
        int r = idx >> 4;
        srow[j] = ((rowb + r) >> 7) * NK + sp[r];
    }

    double acc[8][4];
    #pragma unroll
    for (int i = 0; i < 8; ++i)
        #pragma unroll
        for (int c = 0; c < 4; ++c) acc[i][c] = 0.0;

    const double* wsb = Wsw + (size_t)cbk * NH * 128;

    for (int kc = 0; kc < NH; kc += 32) {
        #pragma unroll
        for (int j = 0; j < 8; ++j) {          // W tile: 2048 double2 copies, linear b128
            int idx = j * 256 + t;
            int row = idx >> 6, cp = idx & 63;
            double2 d = *(const double2*)&wsb[(size_t)(kc + row) * 128 + 2 * cp];
            *(double2*)&wt[row][2 * cp] = d;
        }
        #pragma unroll
        for (int j = 0; j < 4; ++j) {          // S tile (gathered): float2 -> double2, linear b128
            int idx = j * 256 + t;
            int r = idx >> 4, cp = idx & 15;
            float2 v = *(const float2*)&states_in[(size_t)srow[j] * NH + kc + 2 * cp];
            double2 d; d.x = (double)v.x; d.y = (double)v.y;
            *(double2*)&st[r][2 * cp] = d;
        }
        __syncthreads();
        #pragma unroll 2
        for (int hh = 0; hh < 32; hh += 2) {
            double w00 = wt[hh][tc],    w01 = wt[hh][tc+32],
                   w02 = wt[hh][tc+64], w03 = wt[hh][tc+96];
            double w10 = wt[hh+1][tc],    w11 = wt[hh+1][tc+32],
                   w12 = wt[hh+1][tc+64], w13 = wt[hh+1][tc+96];
            #pragma unroll
            for (int i = 0; i < 8; ++i) {
                double2 s = *(const double2*)&st[rg*8+i][hh];
                acc[i][0] = fma(s.x, w00, acc[i][0]);
                acc[i][1] = fma(s.x, w01, acc[i][1]);
                acc[i][2] = fma(s.x, w02, acc[i][2]);
                acc[i][3] = fma(s.x, w03, acc[i][3]);
                acc[i][0] = fma(s.y, w10, acc[i][0]);
                acc[i][1] = fma(s.y, w11, acc[i][1]);
                acc[i][2] = fma(s.y, w12, acc[i][2]);
                acc[i][3] = fma(s.y, w13, acc[i][3]);
            }
        }
        __syncthreads();
    }

    #pragma unroll
    for (int c = 0; c < 4; ++c) {
        int col = colb + tc + 32 * c;
        double bb = (double)bhh[col];
        #pragma unroll
        for (int i = 0; i < 8; ++i) {
            int r = rg * 8 + i;
            double e = (double)emb[(size_t)sd[r] * NH + col];
            double z = acc[i][c] + bb + e;
            states_out[(size_t)(rowb + r) * NH + col] = (float)tanh(z);
        }
    }
}

// ---------------- finalize: d_out = [hist as float (524288), scores as float (32768)]
__global__ void k_final(const unsigned char* __restrict__ hist,
                        const double* __restrict__ scores,
                        float* __restrict__ out)
{
    int i = blockIdx.x * 256 + threadIdx.x;
    const int nh = BKROWS * NDEPTH;      // 524288
    if (i < nh) out[i] = (float)hist[i];
    else if (i < nh + BKROWS) out[i] = (float)scores[i - nh];
}

extern "C" void kernel_launch(void* const* d_in, const int* in_sizes, int n_in,
                              void* d_out, int out_size, void* d_ws, size_t ws_size,
                              hipStream_t stream) {
    // inputs: env(unused), root_state, W_logits, b_logits, W_hh, b_hh, emb, beams(=128)
    const float* root = (const float*)d_in[1];
    const float* Wl   = (const float*)d_in[2];
    const float* bl   = (const float*)d_in[3];
    const float* Whh  = (const float*)d_in[4];
    const float* bhh  = (const float*)d_in[5];
    const float* emb  = (const float*)d_in[6];

    char* ws = (char*)d_ws;
    double* Wsw          = (double*)(ws + 0);             //  2,097,152
    double* Wld          = (double*)(ws + 2097152);       //    262,144
    double* cand         = (double*)(ws + 2359296);       // 16,777,216
    double* scores       = (double*)(ws + 19136512);      //    262,144
    float*  sA           = (float*)(ws + 19398656);       // 67,108,864
    float*  sB           = (float*)(ws + 86507520);       // 67,108,864
    int*    parent       = (int*)(ws + 153616384);        //    131,072
    int*    decs         = (int*)(ws + 153747456);        //    131,072
    unsigned char* hA    = (unsigned char*)(ws + 153878528); // 524,288
    unsigned char* hB    = (unsigned char*)(ws + 154402816); // 524,288
    // total 154,927,104 bytes (<= round-1/2 proven footprint)

    k_prep<<<1024, 256, 0, stream>>>(Whh, Wl, Wsw, Wld);
    k_init<<<65536, 256, 0, stream>>>(root, sA, scores, hA);

    float* scur = sA; float* snxt = sB;
    unsigned char* hcur = hA; unsigned char* hnxt = hB;
    for (int t = 0; t < NDEPTH; ++t) {
        k_logits<<<512, 256, 0, stream>>>(scur, Wld, bl, scores, cand);
        k_topk<<<256, 256, 0, stream>>>(cand, scores, parent, decs, hcur, hnxt, t);
        k_rnn<<<dim3(512, 4), 256, 0, stream>>>(scur, Wsw, bhh, emb, parent, decs, snxt);
        { float* tmp = scur; scur = snxt; snxt = tmp; }
        { unsigned char* tmp = hcur; hcur = hnxt; hnxt = tmp; }
    }

    k_final<<<2176, 256, 0, stream>>>(hcur, scores, (float*)d_out);
}